// Round 1
// baseline (10507.092 us; speedup 1.0000x reference)
//
#include <hip/hip_runtime.h>

#define M_EDGES 150000
#define NN_NODES 50000
#define N_TRIS  100000
#define F 256
#define NLAYERS 4

// ---------------------------------------------------------------------------
// Fused GEMM: X (M x 256) @ [W0 | W1 | W2] (256 x 768)
//   blockIdx.y 0..3  -> W0 columns: epilogue = atomic scatter into z (B1 apply)
//   blockIdx.y 4..7  -> W1 columns: epilogue = store into acc
//   blockIdx.y 8..11 -> W2 columns: epilogue = store into y2
// Tile 64x64, BK=32, 256 threads, 4x4 per thread.
// ---------------------------------------------------------------------------
__global__ __launch_bounds__(256) void gemm_fused(
    const float* __restrict__ X,
    const float* __restrict__ W0,
    const float* __restrict__ W1,
    const float* __restrict__ W2,
    const int* __restrict__ en,
    float* __restrict__ z,
    float* __restrict__ acc,
    float* __restrict__ y2)
{
    __shared__ float As[64][36];   // [m][k], pad 36 -> 16B-aligned rows, 2-way-free banks
    __shared__ float Bs[32][64];   // [k][n]

    const int tid = threadIdx.x;
    const int ty = tid >> 4;       // 0..15 -> row group
    const int tx = tid & 15;       // 0..15 -> col group
    const int bm0 = blockIdx.x * 64;
    const int by = blockIdx.y;

    const float* Wp;
    int colbase;
    if (by < 4)      { Wp = W0; colbase = by * 64; }
    else if (by < 8) { Wp = W1; colbase = (by - 4) * 64; }
    else             { Wp = W2; colbase = (by - 8) * 64; }

    float c[4][4] = {};

    for (int k0 = 0; k0 < 256; k0 += 32) {
#pragma unroll
        for (int r = 0; r < 2; r++) {
            int idx = tid + 256 * r;
            // A tile: 64 rows x 32 k  (512 float4)
            int arow = idx >> 3;
            int ak   = (idx & 7) * 4;
            float4 av = make_float4(0.f, 0.f, 0.f, 0.f);
            int gr = bm0 + arow;
            if (gr < M_EDGES) av = *(const float4*)(X + (size_t)gr * F + k0 + ak);
            *(float4*)(&As[arow][ak]) = av;
            // B tile: 32 k x 64 cols  (512 float4)
            int bk = idx >> 4;
            int bn = (idx & 15) * 4;
            float4 bv = *(const float4*)(Wp + (size_t)(k0 + bk) * F + colbase + bn);
            *(float4*)(&Bs[bk][bn]) = bv;
        }
        __syncthreads();
#pragma unroll
        for (int kk = 0; kk < 32; kk++) {
            float4 b4 = *(const float4*)(&Bs[kk][tx * 4]);
#pragma unroll
            for (int i = 0; i < 4; i++) {
                float a = As[ty * 4 + i][kk];
                c[i][0] += a * b4.x;
                c[i][1] += a * b4.y;
                c[i][2] += a * b4.z;
                c[i][3] += a * b4.w;
            }
        }
        __syncthreads();
    }

    if (by < 4) {
        // y0 path: scatter-add into node accumulator z (B1: z[u]-=y0, z[v]+=y0)
#pragma unroll
        for (int i = 0; i < 4; i++) {
            int gr = bm0 + ty * 4 + i;
            if (gr >= M_EDGES) break;
            int u = en[2 * gr];
            int v = en[2 * gr + 1];
            int f = colbase + tx * 4;
#pragma unroll
            for (int j = 0; j < 4; j++) {
                float val = c[i][j];
                atomicAdd(z + (size_t)u * F + f + j, -val);
                atomicAdd(z + (size_t)v * F + f + j,  val);
            }
        }
    } else {
        float* dst = (by < 8) ? acc : y2;
#pragma unroll
        for (int i = 0; i < 4; i++) {
            int gr = bm0 + ty * 4 + i;
            if (gr >= M_EDGES) break;
            *(float4*)(dst + (size_t)gr * F + colbase + tx * 4) =
                make_float4(c[i][0], c[i][1], c[i][2], c[i][3]);
        }
    }
}

// ---------------------------------------------------------------------------
// Triangle kernel: w[t] = sum_k s_k * y2[e_k]; acc[e_k] += s_k * w[t]
// One wave (64 lanes) per triangle; lane handles a float4 (f = lane*4).
// ---------------------------------------------------------------------------
__global__ __launch_bounds__(256) void tri_kernel(
    const float* __restrict__ y2,
    const int* __restrict__ te,
    const int* __restrict__ ts,
    float* __restrict__ acc)
{
    int t = blockIdx.x * 4 + (threadIdx.x >> 6);
    int lane = threadIdx.x & 63;
    if (t >= N_TRIS) return;
    int e0 = te[3 * t + 0];
    int e1 = te[3 * t + 1];
    int e2 = te[3 * t + 2];
    float s0 = (float)ts[3 * t + 0];
    float s1 = (float)ts[3 * t + 1];
    float s2 = (float)ts[3 * t + 2];
    int f = lane * 4;

    float4 a = *(const float4*)(y2 + (size_t)e0 * F + f);
    float4 b = *(const float4*)(y2 + (size_t)e1 * F + f);
    float4 d = *(const float4*)(y2 + (size_t)e2 * F + f);

    float4 w;
    w.x = s0 * a.x + s1 * b.x + s2 * d.x;
    w.y = s0 * a.y + s1 * b.y + s2 * d.y;
    w.z = s0 * a.z + s1 * b.z + s2 * d.z;
    w.w = s0 * a.w + s1 * b.w + s2 * d.w;

    float* p0 = acc + (size_t)e0 * F + f;
    float* p1 = acc + (size_t)e1 * F + f;
    float* p2 = acc + (size_t)e2 * F + f;
    atomicAdd(p0 + 0, s0 * w.x); atomicAdd(p0 + 1, s0 * w.y);
    atomicAdd(p0 + 2, s0 * w.z); atomicAdd(p0 + 3, s0 * w.w);
    atomicAdd(p1 + 0, s1 * w.x); atomicAdd(p1 + 1, s1 * w.y);
    atomicAdd(p1 + 2, s1 * w.z); atomicAdd(p1 + 3, s1 * w.w);
    atomicAdd(p2 + 0, s2 * w.x); atomicAdd(p2 + 1, s2 * w.y);
    atomicAdd(p2 + 2, s2 * w.z); atomicAdd(p2 + 3, s2 * w.w);
}

// ---------------------------------------------------------------------------
// ReLU + B1^T gather: x_next[e] = relu(acc[e] + z[v(e)] - z[u(e)])  (in place)
// ---------------------------------------------------------------------------
__global__ __launch_bounds__(256) void relu_kernel(
    float* __restrict__ a,
    const float* __restrict__ z,
    const int* __restrict__ en)
{
    int idx = blockIdx.x * 256 + threadIdx.x;   // M*64 threads, each a float4
    int e = idx >> 6;
    int f = (idx & 63) * 4;
    int u = en[2 * e];
    int v = en[2 * e + 1];
    float4 av = *(const float4*)(a + (size_t)e * F + f);
    float4 zv = *(const float4*)(z + (size_t)v * F + f);
    float4 zu = *(const float4*)(z + (size_t)u * F + f);
    float4 r;
    r.x = fmaxf(av.x + zv.x - zu.x, 0.f);
    r.y = fmaxf(av.y + zv.y - zu.y, 0.f);
    r.z = fmaxf(av.z + zv.z - zu.z, 0.f);
    r.w = fmaxf(av.w + zv.w - zu.w, 0.f);
    *(float4*)(a + (size_t)e * F + f) = r;
}

// ---------------------------------------------------------------------------
// Final: p[e] = x[e] . W0_L ; out[u(e)] -= p ; out[v(e)] += p
// One wave per edge.
// ---------------------------------------------------------------------------
__global__ __launch_bounds__(256) void final_kernel(
    const float* __restrict__ x,
    const float* __restrict__ wl,
    const int* __restrict__ en,
    float* __restrict__ out)
{
    int e = blockIdx.x * 4 + (threadIdx.x >> 6);
    int lane = threadIdx.x & 63;
    if (e >= M_EDGES) return;
    float4 xv = *(const float4*)(x + (size_t)e * F + lane * 4);
    float4 wv = *(const float4*)(wl + lane * 4);
    float s = xv.x * wv.x + xv.y * wv.y + xv.z * wv.z + xv.w * wv.w;
#pragma unroll
    for (int off = 32; off > 0; off >>= 1)
        s += __shfl_down(s, off, 64);
    if (lane == 0) {
        atomicAdd(out + en[2 * e], -s);
        atomicAdd(out + en[2 * e + 1], s);
    }
}

extern "C" void kernel_launch(void* const* d_in, const int* in_sizes, int n_in,
                              void* d_out, int out_size, void* d_ws, size_t ws_size,
                              hipStream_t stream)
{
    const float* x0  = (const float*)d_in[0];
    const float* W0s = (const float*)d_in[1];
    const float* W1s = (const float*)d_in[2];
    const float* W2s = (const float*)d_in[3];
    const float* WL  = (const float*)d_in[4];
    const int*   en  = (const int*)d_in[5];
    const int*   te  = (const int*)d_in[6];
    const int*   ts  = (const int*)d_in[7];
    float* out = (float*)d_out;

    const size_t MF = (size_t)M_EDGES * F;
    float* bufA = (float*)d_ws;
    float* bufB = bufA + MF;
    float* y2   = bufB + MF;
    float* z    = y2 + MF;          // NN_NODES * F floats

    dim3 ggrid((M_EDGES + 63) / 64, 12);   // 2344 x 12

    for (int l = 0; l < NLAYERS; l++) {
        const float* xin = (l == 0) ? x0 : ((l & 1) ? bufA : bufB);
        float* acc = (l & 1) ? bufB : bufA;
        hipMemsetAsync(z, 0, (size_t)NN_NODES * F * sizeof(float), stream);
        gemm_fused<<<ggrid, 256, 0, stream>>>(
            xin,
            W0s + (size_t)l * F * F,
            W1s + (size_t)l * F * F,
            W2s + (size_t)l * F * F,
            en, z, acc, y2);
        tri_kernel<<<(N_TRIS + 3) / 4, 256, 0, stream>>>(y2, te, ts, acc);
        relu_kernel<<<(M_EDGES * 64) / 256, 256, 0, stream>>>(acc, z, en);
    }

    hipMemsetAsync(out, 0, NN_NODES * sizeof(float), stream);
    final_kernel<<<(M_EDGES + 3) / 4, 256, 0, stream>>>(bufB, WL, en, out);
}

// Round 2
// 9088.985 us; speedup vs baseline: 1.1560x; 1.1560x over previous
//
#include <hip/hip_runtime.h>

#define M_EDGES 150000
#define NN_NODES 50000
#define N_TRIS  100000
#define F 256
#define NLAYERS 4

typedef __attribute__((ext_vector_type(8))) __bf16 bf16x8;
typedef __attribute__((ext_vector_type(4))) float f32x4;

__device__ inline unsigned short f2bf(float f) {
    unsigned int u = __float_as_uint(f);
    u += 0x7fff + ((u >> 16) & 1);
    return (unsigned short)(u >> 16);
}
__device__ inline float bf2f(unsigned short h) {
    return __uint_as_float(((unsigned int)h) << 16);
}

__device__ inline void async16(const void* g, void* l) {
    __builtin_amdgcn_global_load_lds(
        (const __attribute__((address_space(1))) void*)g,
        (__attribute__((address_space(3))) void*)l, 16, 0, 0);
}

// ---------------------------------------------------------------------------
// bf16 MFMA GEMM: X (M x 256, bf16) @ WcatT^T, WcatT is (768 x 256, bf16,
// n-major = B^T layout). Block = 128x128 tile of C; grid.y = 6 column blocks:
//   bn 0,1 -> y0 (bf16 store)   bn 2,3 -> acc (f32 store)   bn 4,5 -> y2 (bf16)
// 256 threads = 4 waves in 2x2, each wave 64x64 via 4x4 grid of 16x16x32 MFMA.
// Staging via global_load_lds width=16 (LDS layout = contiguous [row][32k]).
// ---------------------------------------------------------------------------
__global__ __launch_bounds__(256) void gemm_mfma(
    const unsigned short* __restrict__ xb,
    const unsigned short* __restrict__ wt,
    unsigned short* __restrict__ y0,
    float* __restrict__ acc,
    unsigned short* __restrict__ y2)
{
    __shared__ unsigned short As[128 * 32];  // 8 KB
    __shared__ unsigned short Bs[128 * 32];  // 8 KB

    const int tid  = threadIdx.x;
    const int bm0  = blockIdx.x * 128;
    const int bn   = blockIdx.y;            // 0..5
    const int wid  = tid >> 6;
    const int lane = tid & 63;
    const int lm   = lane & 15;
    const int lh   = lane >> 4;
    const int wm   = wid >> 1;
    const int wn   = wid & 1;
    const int wbase = tid & ~63;            // wave-uniform

    f32x4 c[4][4];
#pragma unroll
    for (int i = 0; i < 4; i++)
#pragma unroll
        for (int j = 0; j < 4; j++) c[i][j] = (f32x4){0.f, 0.f, 0.f, 0.f};

    for (int k0 = 0; k0 < 256; k0 += 32) {
        // ---- stage A and B tiles: 2 call sites each, 16B/lane ----
#pragma unroll
        for (int s = 0; s < 2; s++) {
            int i   = s * 256 + tid;        // 0..511, one 16B granule each
            int row = i >> 2;               // 0..127
            int q   = i & 3;                // 16B quarter within 64B row
            int gr  = bm0 + row;
            if (gr > M_EDGES - 1) gr = M_EDGES - 1;
            async16(xb + (size_t)gr * 256 + k0 + q * 8,
                    As + (size_t)(s * 256 + wbase) * 8);
            int nrow = bn * 128 + row;      // < 768 always
            async16(wt + (size_t)nrow * 256 + k0 + q * 8,
                    Bs + (size_t)(s * 256 + wbase) * 8);
        }
        asm volatile("s_waitcnt vmcnt(0)" ::: "memory");
        __syncthreads();

        bf16x8 a[4], b[4];
#pragma unroll
        for (int i = 0; i < 4; i++)
            a[i] = *(const bf16x8*)(As + ((wm * 64 + i * 16 + lm) * 32 + lh * 8));
#pragma unroll
        for (int j = 0; j < 4; j++)
            b[j] = *(const bf16x8*)(Bs + ((wn * 64 + j * 16 + lm) * 32 + lh * 8));
#pragma unroll
        for (int i = 0; i < 4; i++)
#pragma unroll
            for (int j = 0; j < 4; j++)
                c[i][j] = __builtin_amdgcn_mfma_f32_16x16x32_bf16(a[i], b[j], c[i][j], 0, 0, 0);
        __syncthreads();
    }

    // ---- epilogue: D layout col=lane&15, row=(lane>>4)*4+reg ----
    const int seg = bn >> 1;   // 0:y0  1:acc  2:y2
    const int colbase = (bn * 128 + wn * 64) & 255;
#pragma unroll
    for (int i = 0; i < 4; i++) {
#pragma unroll
        for (int r = 0; r < 4; r++) {
            int grow = bm0 + wm * 64 + i * 16 + lh * 4 + r;
            if (grow < M_EDGES) {
#pragma unroll
                for (int j = 0; j < 4; j++) {
                    int col = colbase + j * 16 + lm;
                    float v = c[i][j][r];
                    if (seg == 0)      y0[(size_t)grow * 256 + col] = f2bf(v);
                    else if (seg == 1) acc[(size_t)grow * 256 + col] = v;
                    else               y2[(size_t)grow * 256 + col] = f2bf(v);
                }
            }
        }
    }
}

// ---------------------------------------------------------------------------
// B1 apply: z[u] -= y0[e], z[v] += y0[e].  One wave per edge, lane = 4 feats.
// ---------------------------------------------------------------------------
__global__ __launch_bounds__(256) void scatter_b1(
    const unsigned short* __restrict__ y0,
    const int* __restrict__ en,
    float* __restrict__ z)
{
    int e = blockIdx.x * 4 + (threadIdx.x >> 6);
    int lane = threadIdx.x & 63;
    if (e >= M_EDGES) return;
    int u = en[2 * e], v = en[2 * e + 1];
    int f = lane * 4;
    ushort4 yv = *(const ushort4*)(y0 + (size_t)e * 256 + f);
    float a = bf2f(yv.x), b = bf2f(yv.y), cc = bf2f(yv.z), d = bf2f(yv.w);
    float* zu = z + (size_t)u * 256 + f;
    float* zv = z + (size_t)v * 256 + f;
    atomicAdd(zu + 0, -a); atomicAdd(zu + 1, -b);
    atomicAdd(zu + 2, -cc); atomicAdd(zu + 3, -d);
    atomicAdd(zv + 0,  a); atomicAdd(zv + 1,  b);
    atomicAdd(zv + 2,  cc); atomicAdd(zv + 3,  d);
}

// ---------------------------------------------------------------------------
// Triangle: w[t] = sum_k s_k * y2[e_k]; acc[e_k] += s_k * w[t]
// ---------------------------------------------------------------------------
__global__ __launch_bounds__(256) void tri_kernel(
    const unsigned short* __restrict__ y2,
    const int* __restrict__ te,
    const int* __restrict__ ts,
    float* __restrict__ acc)
{
    int t = blockIdx.x * 4 + (threadIdx.x >> 6);
    int lane = threadIdx.x & 63;
    if (t >= N_TRIS) return;
    int e0 = te[3 * t + 0], e1 = te[3 * t + 1], e2 = te[3 * t + 2];
    float s0 = (float)ts[3 * t + 0];
    float s1 = (float)ts[3 * t + 1];
    float s2 = (float)ts[3 * t + 2];
    int f = lane * 4;

    ushort4 a4 = *(const ushort4*)(y2 + (size_t)e0 * 256 + f);
    ushort4 b4 = *(const ushort4*)(y2 + (size_t)e1 * 256 + f);
    ushort4 d4 = *(const ushort4*)(y2 + (size_t)e2 * 256 + f);

    float wx = s0 * bf2f(a4.x) + s1 * bf2f(b4.x) + s2 * bf2f(d4.x);
    float wy = s0 * bf2f(a4.y) + s1 * bf2f(b4.y) + s2 * bf2f(d4.y);
    float wz = s0 * bf2f(a4.z) + s1 * bf2f(b4.z) + s2 * bf2f(d4.z);
    float ww = s0 * bf2f(a4.w) + s1 * bf2f(b4.w) + s2 * bf2f(d4.w);

    float* p0 = acc + (size_t)e0 * 256 + f;
    float* p1 = acc + (size_t)e1 * 256 + f;
    float* p2 = acc + (size_t)e2 * 256 + f;
    atomicAdd(p0 + 0, s0 * wx); atomicAdd(p0 + 1, s0 * wy);
    atomicAdd(p0 + 2, s0 * wz); atomicAdd(p0 + 3, s0 * ww);
    atomicAdd(p1 + 0, s1 * wx); atomicAdd(p1 + 1, s1 * wy);
    atomicAdd(p1 + 2, s1 * wz); atomicAdd(p1 + 3, s1 * ww);
    atomicAdd(p2 + 0, s2 * wx); atomicAdd(p2 + 1, s2 * wy);
    atomicAdd(p2 + 2, s2 * wz); atomicAdd(p2 + 3, s2 * ww);
}

// ---------------------------------------------------------------------------
// ReLU + B1^T gather; writes next-layer bf16 input.
// ---------------------------------------------------------------------------
__global__ __launch_bounds__(256) void relu_kernel(
    const float* __restrict__ a,
    const float* __restrict__ z,
    const int* __restrict__ en,
    unsigned short* __restrict__ xb)
{
    int idx = blockIdx.x * 256 + threadIdx.x;
    int e = idx >> 6;
    int f = (idx & 63) * 4;
    int u = en[2 * e], v = en[2 * e + 1];
    float4 av = *(const float4*)(a + (size_t)e * 256 + f);
    float4 zv = *(const float4*)(z + (size_t)v * 256 + f);
    float4 zu = *(const float4*)(z + (size_t)u * 256 + f);
    ushort4 r;
    r.x = f2bf(fmaxf(av.x + zv.x - zu.x, 0.f));
    r.y = f2bf(fmaxf(av.y + zv.y - zu.y, 0.f));
    r.z = f2bf(fmaxf(av.z + zv.z - zu.z, 0.f));
    r.w = f2bf(fmaxf(av.w + zv.w - zu.w, 0.f));
    *(ushort4*)(xb + (size_t)e * 256 + f) = r;
}

// ---------------------------------------------------------------------------
// Final GEMV + B1 scatter
// ---------------------------------------------------------------------------
__global__ __launch_bounds__(256) void final_kernel(
    const unsigned short* __restrict__ xb,
    const float* __restrict__ wl,
    const int* __restrict__ en,
    float* __restrict__ out)
{
    int e = blockIdx.x * 4 + (threadIdx.x >> 6);
    int lane = threadIdx.x & 63;
    if (e >= M_EDGES) return;
    ushort4 xv = *(const ushort4*)(xb + (size_t)e * 256 + lane * 4);
    float4 wv = *(const float4*)(wl + lane * 4);
    float s = bf2f(xv.x) * wv.x + bf2f(xv.y) * wv.y +
              bf2f(xv.z) * wv.z + bf2f(xv.w) * wv.w;
#pragma unroll
    for (int off = 32; off > 0; off >>= 1)
        s += __shfl_down(s, off, 64);
    if (lane == 0) {
        atomicAdd(out + en[2 * e], -s);
        atomicAdd(out + en[2 * e + 1], s);
    }
}

// ---------------------------------------------------------------------------
// Conversions
// ---------------------------------------------------------------------------
__global__ __launch_bounds__(256) void cvt_x(
    const float* __restrict__ x, unsigned short* __restrict__ xb)
{
    int idx = blockIdx.x * 256 + threadIdx.x;   // each handles 4 floats
    float4 v = *(const float4*)(x + (size_t)idx * 4);
    ushort4 r;
    r.x = f2bf(v.x); r.y = f2bf(v.y); r.z = f2bf(v.z); r.w = f2bf(v.w);
    *(ushort4*)(xb + (size_t)idx * 4) = r;
}

// WcatT[l][n][k] (bf16) from W{0,1,2}_stack[l][k][n] (f32)
__global__ __launch_bounds__(256) void cvt_w(
    const float* __restrict__ W0, const float* __restrict__ W1,
    const float* __restrict__ W2, unsigned short* __restrict__ wt)
{
    int idx = blockIdx.x * 256 + threadIdx.x;   // 4 * 768 * 256 total
    int l = idx / (768 * 256);
    int rem = idx - l * (768 * 256);
    int n = rem >> 8;
    int k = rem & 255;
    const float* src;
    int nn;
    if (n < 256)      { src = W0; nn = n; }
    else if (n < 512) { src = W1; nn = n - 256; }
    else              { src = W2; nn = n - 512; }
    float v = src[(size_t)l * 65536 + k * 256 + nn];
    wt[idx] = f2bf(v);
}

extern "C" void kernel_launch(void* const* d_in, const int* in_sizes, int n_in,
                              void* d_out, int out_size, void* d_ws, size_t ws_size,
                              hipStream_t stream)
{
    const float* x0  = (const float*)d_in[0];
    const float* W0s = (const float*)d_in[1];
    const float* W1s = (const float*)d_in[2];
    const float* W2s = (const float*)d_in[3];
    const float* WL  = (const float*)d_in[4];
    const int*   en  = (const int*)d_in[5];
    const int*   te  = (const int*)d_in[6];
    const int*   ts  = (const int*)d_in[7];
    float* out = (float*)d_out;

    const size_t MF = (size_t)M_EDGES * F;          // 38.4M elems
    unsigned short* xb = (unsigned short*)d_ws;     // MF bf16
    unsigned short* y0 = xb + MF;                   // MF bf16
    unsigned short* y2 = y0 + MF;                   // MF bf16
    unsigned short* wt = y2 + MF;                   // 4*768*256 bf16
    float* acc = (float*)(wt + 4 * 768 * 256);      // MF f32
    float* z   = acc + MF;                          // NN*F f32

    cvt_w<<<(4 * 768 * 256) / 256, 256, 0, stream>>>(W0s, W1s, W2s, wt);
    cvt_x<<<(int)(MF / 4 / 256), 256, 0, stream>>>(x0, xb);

    dim3 ggrid((M_EDGES + 127) / 128, 6);           // 1172 x 6

    for (int l = 0; l < NLAYERS; l++) {
        hipMemsetAsync(z, 0, (size_t)NN_NODES * F * sizeof(float), stream);
        gemm_mfma<<<ggrid, 256, 0, stream>>>(
            xb, wt + (size_t)l * 768 * 256, y0, acc, y2);
        scatter_b1<<<(M_EDGES + 3) / 4, 256, 0, stream>>>(y0, en, z);
        tri_kernel<<<(N_TRIS + 3) / 4, 256, 0, stream>>>(y2, te, ts, acc);
        relu_kernel<<<(M_EDGES * 64) / 256, 256, 0, stream>>>(acc, z, en, xb);
    }

    hipMemsetAsync(out, 0, NN_NODES * sizeof(float), stream);
    final_kernel<<<(M_EDGES + 3) / 4, 256, 0, stream>>>(xb, WL, en, out);
}

// Round 3
// 1597.163 us; speedup vs baseline: 6.5786x; 5.6907x over previous
//
#include <hip/hip_runtime.h>

#define M_EDGES 150000
#define NN_NODES 50000
#define N_TRIS  100000
#define F 256
#define NLAYERS 4

typedef __attribute__((ext_vector_type(8))) __bf16 bf16x8;
typedef __attribute__((ext_vector_type(4))) float f32x4;

__device__ inline unsigned short f2bf(float f) {
    unsigned int u = __float_as_uint(f);
    u += 0x7fff + ((u >> 16) & 1);
    return (unsigned short)(u >> 16);
}
__device__ inline float bf2f(unsigned short h) {
    return __uint_as_float(((unsigned int)h) << 16);
}

__device__ inline void async16(const void* g, void* l) {
    __builtin_amdgcn_global_load_lds(
        (const __attribute__((address_space(1))) void*)g,
        (__attribute__((address_space(3))) void*)l, 16, 0, 0);
}

// ---------------------------------------------------------------------------
// bf16 MFMA GEMM: X (M x 256) @ WcatT^T  (WcatT: 768 x 256, n-major).
// grid.y: 0,1 -> y0   2,3 -> y1   4,5 -> y2   (all bf16 stores)
// ---------------------------------------------------------------------------
__global__ __launch_bounds__(256) void gemm_mfma(
    const unsigned short* __restrict__ xb,
    const unsigned short* __restrict__ wt,
    unsigned short* __restrict__ y0,
    unsigned short* __restrict__ y1,
    unsigned short* __restrict__ y2)
{
    __shared__ unsigned short As[128 * 32];
    __shared__ unsigned short Bs[128 * 32];

    const int tid  = threadIdx.x;
    const int bm0  = blockIdx.x * 128;
    const int bn   = blockIdx.y;
    const int wid  = tid >> 6;
    const int lane = tid & 63;
    const int lm   = lane & 15;
    const int lh   = lane >> 4;
    const int wm   = wid >> 1;
    const int wn   = wid & 1;
    const int wbase = tid & ~63;

    f32x4 c[4][4];
#pragma unroll
    for (int i = 0; i < 4; i++)
#pragma unroll
        for (int j = 0; j < 4; j++) c[i][j] = (f32x4){0.f, 0.f, 0.f, 0.f};

    for (int k0 = 0; k0 < 256; k0 += 32) {
#pragma unroll
        for (int s = 0; s < 2; s++) {
            int i   = s * 256 + tid;
            int row = i >> 2;
            int q   = i & 3;
            int gr  = bm0 + row;
            if (gr > M_EDGES - 1) gr = M_EDGES - 1;
            async16(xb + (size_t)gr * 256 + k0 + q * 8,
                    As + (size_t)(s * 256 + wbase) * 8);
            int nrow = bn * 128 + row;
            async16(wt + (size_t)nrow * 256 + k0 + q * 8,
                    Bs + (size_t)(s * 256 + wbase) * 8);
        }
        asm volatile("s_waitcnt vmcnt(0)" ::: "memory");
        __syncthreads();

        bf16x8 a[4], b[4];
#pragma unroll
        for (int i = 0; i < 4; i++)
            a[i] = *(const bf16x8*)(As + ((wm * 64 + i * 16 + lm) * 32 + lh * 8));
#pragma unroll
        for (int j = 0; j < 4; j++)
            b[j] = *(const bf16x8*)(Bs + ((wn * 64 + j * 16 + lm) * 32 + lh * 8));
#pragma unroll
        for (int i = 0; i < 4; i++)
#pragma unroll
            for (int j = 0; j < 4; j++)
                c[i][j] = __builtin_amdgcn_mfma_f32_16x16x32_bf16(a[i], b[j], c[i][j], 0, 0, 0);
        __syncthreads();
    }

    const int seg = bn >> 1;
    unsigned short* dst = (seg == 0) ? y0 : (seg == 1) ? y1 : y2;
    const int colbase = (bn * 128 + wn * 64) & 255;
#pragma unroll
    for (int i = 0; i < 4; i++) {
#pragma unroll
        for (int r = 0; r < 4; r++) {
            int grow = bm0 + wm * 64 + i * 16 + lh * 4 + r;
            if (grow < M_EDGES) {
#pragma unroll
                for (int j = 0; j < 4; j++) {
                    int col = colbase + j * 16 + lm;
                    dst[(size_t)grow * 256 + col] = f2bf(c[i][j][r]);
                }
            }
        }
    }
}

// ---------------------------------------------------------------------------
// CSR build: counts -> exclusive scan (3 kernels) -> fill
// ---------------------------------------------------------------------------
__global__ __launch_bounds__(256) void count_nodes(
    const int* __restrict__ en, int* __restrict__ cnt)
{
    int e = blockIdx.x * 256 + threadIdx.x;
    if (e < M_EDGES) {
        atomicAdd(&cnt[en[2 * e]], 1);
        atomicAdd(&cnt[en[2 * e + 1]], 1);
    }
}

__global__ __launch_bounds__(256) void count_tris(
    const int* __restrict__ te, int* __restrict__ cnt)
{
    int t = blockIdx.x * 256 + threadIdx.x;
    if (t < N_TRIS) {
#pragma unroll
        for (int k = 0; k < 3; k++) atomicAdd(&cnt[te[3 * t + k]], 1);
    }
}

__global__ __launch_bounds__(256) void scan_block(
    const int* __restrict__ cnt, int* __restrict__ off,
    int* __restrict__ partial, int n)
{
    __shared__ int s[256];
    int t = threadIdx.x;
    int gid = blockIdx.x * 256 + t;
    int v = (gid < n) ? cnt[gid] : 0;
    s[t] = v;
    __syncthreads();
    for (int o = 1; o < 256; o <<= 1) {
        int x = (t >= o) ? s[t - o] : 0;
        __syncthreads();
        s[t] += x;
        __syncthreads();
    }
    if (gid < n) off[gid] = s[t] - v;
    if (t == 255) partial[blockIdx.x] = s[255];
}

__global__ __launch_bounds__(1024) void scan_partial(int* __restrict__ partial, int nb)
{
    __shared__ int s[1024];
    int t = threadIdx.x;
    int v = (t < nb) ? partial[t] : 0;
    s[t] = v;
    __syncthreads();
    for (int o = 1; o < 1024; o <<= 1) {
        int x = (t >= o) ? s[t - o] : 0;
        __syncthreads();
        s[t] += x;
        __syncthreads();
    }
    if (t < nb) partial[t] = s[t] - v;
}

__global__ __launch_bounds__(256) void scan_add(
    int* __restrict__ off, int* __restrict__ cursor,
    const int* __restrict__ partial, int n, int total)
{
    int gid = blockIdx.x * 256 + threadIdx.x;
    if (gid == 0) off[n] = total;
    if (gid < n) {
        int o = off[gid] + partial[blockIdx.x];
        off[gid] = o;
        cursor[gid] = o;
    }
}

__global__ __launch_bounds__(256) void fill_nodes(
    const int* __restrict__ en, int* __restrict__ cursor, int* __restrict__ adj)
{
    int e = blockIdx.x * 256 + threadIdx.x;
    if (e < M_EDGES) {
        int u = en[2 * e], v = en[2 * e + 1];
        adj[atomicAdd(&cursor[u], 1)] = (e << 1);        // u endpoint: minus
        adj[atomicAdd(&cursor[v], 1)] = (e << 1) | 1;    // v endpoint: plus
    }
}

__global__ __launch_bounds__(256) void fill_tris(
    const int* __restrict__ te, const int* __restrict__ ts,
    int* __restrict__ cursor, int* __restrict__ adj)
{
    int t = blockIdx.x * 256 + threadIdx.x;
    if (t < N_TRIS) {
#pragma unroll
        for (int k = 0; k < 3; k++) {
            int e = te[3 * t + k];
            int neg = (ts[3 * t + k] < 0) ? 1 : 0;
            adj[atomicAdd(&cursor[e], 1)] = (t << 1) | neg;
        }
    }
}

// ---------------------------------------------------------------------------
// w[t] = sum_k s_k * y2[e_k]   (gather, bf16 out)
// ---------------------------------------------------------------------------
__global__ __launch_bounds__(256) void w_tri(
    const unsigned short* __restrict__ y2,
    const int* __restrict__ te,
    const int* __restrict__ ts,
    unsigned short* __restrict__ w)
{
    int t = blockIdx.x * 4 + (threadIdx.x >> 6);
    int lane = threadIdx.x & 63;
    int e0 = te[3 * t + 0], e1 = te[3 * t + 1], e2 = te[3 * t + 2];
    float s0 = (float)ts[3 * t + 0];
    float s1 = (float)ts[3 * t + 1];
    float s2 = (float)ts[3 * t + 2];
    int f = lane * 4;
    ushort4 a4 = *(const ushort4*)(y2 + (size_t)e0 * 256 + f);
    ushort4 b4 = *(const ushort4*)(y2 + (size_t)e1 * 256 + f);
    ushort4 d4 = *(const ushort4*)(y2 + (size_t)e2 * 256 + f);
    ushort4 r;
    r.x = f2bf(s0 * bf2f(a4.x) + s1 * bf2f(b4.x) + s2 * bf2f(d4.x));
    r.y = f2bf(s0 * bf2f(a4.y) + s1 * bf2f(b4.y) + s2 * bf2f(d4.y));
    r.z = f2bf(s0 * bf2f(a4.z) + s1 * bf2f(b4.z) + s2 * bf2f(d4.z));
    r.w = f2bf(s0 * bf2f(a4.w) + s1 * bf2f(b4.w) + s2 * bf2f(d4.w));
    *(ushort4*)(w + (size_t)t * 256 + f) = r;
}

// ---------------------------------------------------------------------------
// z[n] = sum_{(e,dir) in csr(n)} (+/-) y0[e]   (gather, f32 out)
// ---------------------------------------------------------------------------
__global__ __launch_bounds__(256) void z_node(
    const unsigned short* __restrict__ y0,
    const int* __restrict__ noff,
    const int* __restrict__ nadj,
    float* __restrict__ z)
{
    int n = blockIdx.x * 4 + (threadIdx.x >> 6);
    int lane = threadIdx.x & 63;
    int f = lane * 4;
    int beg = noff[n], end = noff[n + 1];
    float ax = 0.f, ay = 0.f, az = 0.f, aw = 0.f;
    for (int i = beg; i < end; i++) {
        int ent = nadj[i];
        int e = ent >> 1;
        float sg = (ent & 1) ? 1.f : -1.f;
        ushort4 yv = *(const ushort4*)(y0 + (size_t)e * 256 + f);
        ax += sg * bf2f(yv.x);
        ay += sg * bf2f(yv.y);
        az += sg * bf2f(yv.z);
        aw += sg * bf2f(yv.w);
    }
    *(float4*)(z + (size_t)n * 256 + f) = make_float4(ax, ay, az, aw);
}

// ---------------------------------------------------------------------------
// x_next[e] = relu( y1[e] + sum_{(t,s) in csr(e)} s*w[t] + z[v]-z[u] )
// ---------------------------------------------------------------------------
__global__ __launch_bounds__(256) void relu_fused(
    const unsigned short* __restrict__ y1,
    const unsigned short* __restrict__ w,
    const float* __restrict__ z,
    const int* __restrict__ en,
    const int* __restrict__ eoff,
    const int* __restrict__ eadj,
    unsigned short* __restrict__ xb)
{
    int e = blockIdx.x * 4 + (threadIdx.x >> 6);
    int lane = threadIdx.x & 63;
    int f = lane * 4;
    ushort4 a4 = *(const ushort4*)(y1 + (size_t)e * 256 + f);
    float sx = bf2f(a4.x), sy = bf2f(a4.y), sz = bf2f(a4.z), sw = bf2f(a4.w);
    int beg = eoff[e], end = eoff[e + 1];
    for (int i = beg; i < end; i++) {
        int ent = eadj[i];
        int t = ent >> 1;
        float sg = (ent & 1) ? -1.f : 1.f;
        ushort4 wv = *(const ushort4*)(w + (size_t)t * 256 + f);
        sx += sg * bf2f(wv.x);
        sy += sg * bf2f(wv.y);
        sz += sg * bf2f(wv.z);
        sw += sg * bf2f(wv.w);
    }
    int u = en[2 * e], v = en[2 * e + 1];
    float4 zv = *(const float4*)(z + (size_t)v * 256 + f);
    float4 zu = *(const float4*)(z + (size_t)u * 256 + f);
    ushort4 r;
    r.x = f2bf(fmaxf(sx + zv.x - zu.x, 0.f));
    r.y = f2bf(fmaxf(sy + zv.y - zu.y, 0.f));
    r.z = f2bf(fmaxf(sz + zv.z - zu.z, 0.f));
    r.w = f2bf(fmaxf(sw + zv.w - zu.w, 0.f));
    *(ushort4*)(xb + (size_t)e * 256 + f) = r;
}

// ---------------------------------------------------------------------------
// p[e] = x[e] . W0_L  (dense store, no atomics)
// ---------------------------------------------------------------------------
__global__ __launch_bounds__(256) void dotp(
    const unsigned short* __restrict__ xb,
    const float* __restrict__ wl,
    float* __restrict__ p)
{
    int e = blockIdx.x * 4 + (threadIdx.x >> 6);
    int lane = threadIdx.x & 63;
    ushort4 xv = *(const ushort4*)(xb + (size_t)e * 256 + lane * 4);
    float4 wv = *(const float4*)(wl + lane * 4);
    float s = bf2f(xv.x) * wv.x + bf2f(xv.y) * wv.y +
              bf2f(xv.z) * wv.z + bf2f(xv.w) * wv.w;
#pragma unroll
    for (int off = 32; off > 0; off >>= 1)
        s += __shfl_down(s, off, 64);
    if (lane == 0) p[e] = s;
}

// out[n] = sum_{(e,dir)} (+/-) p[e]
__global__ __launch_bounds__(256) void out_nodes(
    const float* __restrict__ p,
    const int* __restrict__ noff,
    const int* __restrict__ nadj,
    float* __restrict__ out)
{
    int n = blockIdx.x * 256 + threadIdx.x;
    if (n >= NN_NODES) return;
    int beg = noff[n], end = noff[n + 1];
    float s = 0.f;
    for (int i = beg; i < end; i++) {
        int ent = nadj[i];
        float sg = (ent & 1) ? 1.f : -1.f;
        s += sg * p[ent >> 1];
    }
    out[n] = s;
}

// ---------------------------------------------------------------------------
// Conversions
// ---------------------------------------------------------------------------
__global__ __launch_bounds__(256) void cvt_x(
    const float* __restrict__ x, unsigned short* __restrict__ xb)
{
    int idx = blockIdx.x * 256 + threadIdx.x;
    float4 v = *(const float4*)(x + (size_t)idx * 4);
    ushort4 r;
    r.x = f2bf(v.x); r.y = f2bf(v.y); r.z = f2bf(v.z); r.w = f2bf(v.w);
    *(ushort4*)(xb + (size_t)idx * 4) = r;
}

__global__ __launch_bounds__(256) void cvt_w(
    const float* __restrict__ W0, const float* __restrict__ W1,
    const float* __restrict__ W2, unsigned short* __restrict__ wt)
{
    int idx = blockIdx.x * 256 + threadIdx.x;
    int l = idx / (768 * 256);
    int rem = idx - l * (768 * 256);
    int n = rem >> 8;
    int k = rem & 255;
    const float* src;
    int nn;
    if (n < 256)      { src = W0; nn = n; }
    else if (n < 512) { src = W1; nn = n - 256; }
    else              { src = W2; nn = n - 512; }
    wt[idx] = f2bf(src[(size_t)l * 65536 + k * 256 + nn]);
}

extern "C" void kernel_launch(void* const* d_in, const int* in_sizes, int n_in,
                              void* d_out, int out_size, void* d_ws, size_t ws_size,
                              hipStream_t stream)
{
    const float* x0  = (const float*)d_in[0];
    const float* W0s = (const float*)d_in[1];
    const float* W1s = (const float*)d_in[2];
    const float* W2s = (const float*)d_in[3];
    const float* WL  = (const float*)d_in[4];
    const int*   en  = (const int*)d_in[5];
    const int*   te  = (const int*)d_in[6];
    const int*   ts  = (const int*)d_in[7];
    float* out = (float*)d_out;

    const size_t MF = (size_t)M_EDGES * F;
    unsigned short* xb = (unsigned short*)d_ws;        // MF
    unsigned short* y0 = xb + MF;                      // MF
    unsigned short* y1 = y0 + MF;                      // MF
    unsigned short* y2 = y1 + MF;                      // MF
    unsigned short* wt = y2 + MF;                      // 4*768*256
    unsigned short* wb = wt + (size_t)4 * 768 * 256;   // N_TRIS*256
    float* z = (float*)(wb + (size_t)N_TRIS * 256);    // NN*256 f32
    float* p = z + (size_t)NN_NODES * 256;             // M f32
    int* noff = (int*)(p + M_EDGES);                   // NN+1
    int* ncur = noff + (NN_NODES + 1);                 // NN
    int* nadj = ncur + NN_NODES;                       // 2*M
    int* eoff = nadj + 2 * M_EDGES;                    // M+1
    int* ecur = eoff + (M_EDGES + 1);                  // M
    int* eadj = ecur + M_EDGES;                        // 3*N_TRIS
    int* part = eadj + 3 * N_TRIS;                     // 1024

    // ---- conversions ----
    cvt_w<<<(4 * 768 * 256) / 256, 256, 0, stream>>>(W0s, W1s, W2s, wt);
    cvt_x<<<(int)(MF / 4 / 256), 256, 0, stream>>>(x0, xb);

    // ---- CSR build (node: 50000 bins / edge: 150000 bins) ----
    const int nbN = (NN_NODES + 255) / 256;   // 196
    const int nbE = (M_EDGES + 255) / 256;    // 586
    hipMemsetAsync(ncur, 0, NN_NODES * sizeof(int), stream);
    hipMemsetAsync(ecur, 0, M_EDGES * sizeof(int), stream);
    count_nodes<<<nbE, 256, 0, stream>>>(en, ncur);
    count_tris<<<(N_TRIS + 255) / 256, 256, 0, stream>>>(te, ecur);
    scan_block<<<nbN, 256, 0, stream>>>(ncur, noff, part, NN_NODES);
    scan_partial<<<1, 1024, 0, stream>>>(part, nbN);
    scan_add<<<nbN, 256, 0, stream>>>(noff, ncur, part, NN_NODES, 2 * M_EDGES);
    fill_nodes<<<nbE, 256, 0, stream>>>(en, ncur, nadj);
    scan_block<<<nbE, 256, 0, stream>>>(ecur, eoff, part, M_EDGES);
    scan_partial<<<1, 1024, 0, stream>>>(part, nbE);
    scan_add<<<nbE, 256, 0, stream>>>(eoff, ecur, part, M_EDGES, 3 * N_TRIS);
    fill_tris<<<(N_TRIS + 255) / 256, 256, 0, stream>>>(te, ts, ecur, eadj);

    // ---- layers ----
    dim3 ggrid((M_EDGES + 127) / 128, 6);
    for (int l = 0; l < NLAYERS; l++) {
        gemm_mfma<<<ggrid, 256, 0, stream>>>(
            xb, wt + (size_t)l * 768 * 256, y0, y1, y2);
        w_tri<<<N_TRIS / 4, 256, 0, stream>>>(y2, te, ts, wb);
        z_node<<<NN_NODES / 4, 256, 0, stream>>>(y0, noff, nadj, z);
        relu_fused<<<M_EDGES / 4, 256, 0, stream>>>(y1, wb, z, en, eoff, eadj, xb);
    }

    // ---- final ----
    dotp<<<M_EDGES / 4, 256, 0, stream>>>(xb, WL, p);
    out_nodes<<<(NN_NODES + 255) / 256, 256, 0, stream>>>(p, noff, nadj, out);
}